// Round 5
// baseline (1074.433 us; speedup 1.0000x reference)
//
#include <hip/hip_runtime.h>

#define N_AUTHOR 100000
#define N_FOS    30000
#define N_INST   8000
#define N_PAPER  200000

typedef __attribute__((ext_vector_type(8))) short short8v;
typedef __attribute__((ext_vector_type(4))) float float4v;

__device__ __forceinline__ unsigned short f2bf(float f) {
  unsigned u = __float_as_uint(f);
  u = u + 0x7fffu + ((u >> 16) & 1u);
  return (unsigned short)(u >> 16);
}
#define BF2F(s) __uint_as_float(((unsigned)(unsigned short)(s)) << 16)

__device__ __forceinline__ void acc8(float4v& x, float4v& y, short8v h) {
  x[0] += BF2F(h[0]); x[1] += BF2F(h[1]); x[2] += BF2F(h[2]); x[3] += BF2F(h[3]);
  y[0] += BF2F(h[4]); y[1] += BF2F(h[5]); y[2] += BF2F(h[6]); y[3] += BF2F(h[7]);
}

// ---------------- workspace layout (bytes) ----------------
#define O_CNT    0
#define O_OFFS   3352000
#define O_CURSOR 6704000
#define O_BTOT   10056000
#define O_CSR    10060096
#define O_WT     23260096
#define XB_AUTHOR 23620544
#define XB_FOS    49220544
#define XB_INST   56900544
#define XB_PAPER  58948544
#define O_AGG     110148544
#define WS_NEED_BF  110148544ULL
#define WS_NEED_AGG 324676544ULL
#define NCNT     838000

struct RelTab { const int* src; const int* dst; int E; int base; };
struct Rels { RelTab r[7]; };
struct WPtrs { const float* w[11]; };
struct XCvt { const float* x; unsigned short* xb; int n8; };

__global__ void prep(WPtrs P, unsigned short* __restrict__ wt,
                     int* __restrict__ cnt, XCvt x0, XCvt x1, XCvt x2, XCvt x3,
                     int doX) {
  int gsz = gridDim.x * blockDim.x;
  int gtid = blockIdx.x * blockDim.x + threadIdx.x;
  for (int i = gtid; i < 11 * 16384; i += gsz) {
    int mat = i >> 14, rem = i & 16383;
    int k = rem >> 7, n = rem & 127;
    wt[mat * 16384 + n * 128 + k] = f2bf(P.w[mat][rem]);
  }
  for (int i = gtid; i < NCNT; i += gsz) cnt[i] = 0;
  if (doX) {
    XCvt xc[4] = {x0, x1, x2, x3};
    #pragma unroll
    for (int a = 0; a < 4; ++a) {
      const float* xp = xc[a].x;
      short8v* xbp = (short8v*)xc[a].xb;
      int n8 = xc[a].n8;
      for (int i = gtid; i < n8; i += gsz) {
        float4v v0 = *(const float4v*)(xp + (size_t)i * 8);
        float4v v1 = *(const float4v*)(xp + (size_t)i * 8 + 4);
        short8v h;
        h[0] = (short)f2bf(v0[0]); h[1] = (short)f2bf(v0[1]);
        h[2] = (short)f2bf(v0[2]); h[3] = (short)f2bf(v0[3]);
        h[4] = (short)f2bf(v1[0]); h[5] = (short)f2bf(v1[1]);
        h[6] = (short)f2bf(v1[2]); h[7] = (short)f2bf(v1[3]);
        xbp[i] = h;
      }
    }
  }
}

__global__ void count_k(Rels R, int* __restrict__ cnt) {
  int gsz = gridDim.x * blockDim.x;
  int gtid = blockIdx.x * blockDim.x + threadIdx.x;
  for (int rr = 0; rr < 7; ++rr) {
    const int* dst = R.r[rr].dst;
    int E = R.r[rr].E, base = R.r[rr].base;
    for (int e = gtid; e < E; e += gsz) atomicAdd(&cnt[base + dst[e]], 1);
  }
}

__global__ void scan1(const int* __restrict__ cnt, int* __restrict__ offs,
                      int* __restrict__ btot, int n) {
  __shared__ int sh[256];
  int tid = threadIdx.x;
  int base = blockIdx.x * 2048 + tid * 8;
  int v[8]; int s = 0;
  #pragma unroll
  for (int i = 0; i < 8; ++i) { v[i] = (base + i < n) ? cnt[base + i] : 0; s += v[i]; }
  sh[tid] = s; __syncthreads();
  for (int off = 1; off < 256; off <<= 1) {
    int t = (tid >= off) ? sh[tid - off] : 0;
    __syncthreads();
    sh[tid] += t;
    __syncthreads();
  }
  int excl = sh[tid] - s;
  if (tid == 255) btot[blockIdx.x] = sh[255];
  int run = excl;
  #pragma unroll
  for (int i = 0; i < 8; ++i) { if (base + i < n) offs[base + i] = run; run += v[i]; }
}

__global__ void scan23(int* __restrict__ offs, int* __restrict__ cursor,
                       const int* __restrict__ btot, int nb, int n) {
  __shared__ int sh[512];
  int tid = threadIdx.x;
  int v = (tid < nb) ? btot[tid] : 0;
  sh[tid] = v; __syncthreads();
  for (int off = 1; off < 512; off <<= 1) {
    int t = (tid >= off) ? sh[tid - off] : 0;
    __syncthreads();
    sh[tid] += t;
    __syncthreads();
  }
  int excl = sh[tid] - v;
  __syncthreads();
  sh[tid] = excl;
  __syncthreads();
  int gsz = gridDim.x * 512;
  for (int idx = blockIdx.x * 512 + tid; idx < n; idx += gsz) {
    int val = offs[idx] + sh[idx >> 11];
    offs[idx] = val;
    cursor[idx] = val;
  }
}

__global__ void fill_k(Rels R, int* __restrict__ cursor, int* __restrict__ csr) {
  int gsz = gridDim.x * blockDim.x;
  int gtid = blockIdx.x * blockDim.x + threadIdx.x;
  for (int rr = 0; rr < 7; ++rr) {
    const int* src = R.r[rr].src;
    const int* dst = R.r[rr].dst;
    int E = R.r[rr].E, base = R.r[rr].base;
    for (int e = gtid; e < E; e += gsz) {
      int p = atomicAdd(&cursor[base + dst[e]], 1);
      csr[p] = src[e];
    }
  }
}

// ---------------- wave-per-row aggregation ----------------
struct AggArgs {
  const unsigned short* xb[7];
  const int* offs; const int* cnt; const int* csr;
  unsigned short* agg;
};

__global__ __launch_bounds__(256, 8) void agg_k(AggArgs G) {
  const int w = blockIdx.x * 4 + (threadIdx.x >> 6);
  const int lane = threadIdx.x & 63;
  int rel = (w >= 638000) ? 6 : (w >= 608000) ? 5 : (w >= 408000) ? 4
          : (w >= 308000) ? 3 : (w >= 108000) ? 2 : (w >= 8000) ? 1 : 0;
  const unsigned short* xb = G.xb[rel];
  const int st = G.offs[w];
  const int deg = G.cnt[w];
  const int ce = lane * 2;
  float a0 = 0.f, a1 = 0.f;
  for (int j = 0; j < deg; j += 8) {
    int rem = deg - j;
    int nb = (rem > 8) ? 8 : rem;
    int vidx = 0;
    if (lane < nb) vidx = G.csr[st + j + lane];
    unsigned r0 = 0, r1 = 0, r2 = 0, r3 = 0, r4 = 0, r5 = 0, r6 = 0, r7 = 0;
    int s;
    if (nb > 0) { s = __builtin_amdgcn_readlane(vidx, 0); r0 = *(const unsigned*)(xb + (size_t)s * 128 + ce); }
    if (nb > 1) { s = __builtin_amdgcn_readlane(vidx, 1); r1 = *(const unsigned*)(xb + (size_t)s * 128 + ce); }
    if (nb > 2) { s = __builtin_amdgcn_readlane(vidx, 2); r2 = *(const unsigned*)(xb + (size_t)s * 128 + ce); }
    if (nb > 3) { s = __builtin_amdgcn_readlane(vidx, 3); r3 = *(const unsigned*)(xb + (size_t)s * 128 + ce); }
    if (nb > 4) { s = __builtin_amdgcn_readlane(vidx, 4); r4 = *(const unsigned*)(xb + (size_t)s * 128 + ce); }
    if (nb > 5) { s = __builtin_amdgcn_readlane(vidx, 5); r5 = *(const unsigned*)(xb + (size_t)s * 128 + ce); }
    if (nb > 6) { s = __builtin_amdgcn_readlane(vidx, 6); r6 = *(const unsigned*)(xb + (size_t)s * 128 + ce); }
    if (nb > 7) { s = __builtin_amdgcn_readlane(vidx, 7); r7 = *(const unsigned*)(xb + (size_t)s * 128 + ce); }
    if (nb > 0) { a0 += __uint_as_float(r0 << 16); a1 += __uint_as_float(r0 & 0xffff0000u); }
    if (nb > 1) { a0 += __uint_as_float(r1 << 16); a1 += __uint_as_float(r1 & 0xffff0000u); }
    if (nb > 2) { a0 += __uint_as_float(r2 << 16); a1 += __uint_as_float(r2 & 0xffff0000u); }
    if (nb > 3) { a0 += __uint_as_float(r3 << 16); a1 += __uint_as_float(r3 & 0xffff0000u); }
    if (nb > 4) { a0 += __uint_as_float(r4 << 16); a1 += __uint_as_float(r4 & 0xffff0000u); }
    if (nb > 5) { a0 += __uint_as_float(r5 << 16); a1 += __uint_as_float(r5 & 0xffff0000u); }
    if (nb > 6) { a0 += __uint_as_float(r6 << 16); a1 += __uint_as_float(r6 & 0xffff0000u); }
    if (nb > 7) { a0 += __uint_as_float(r7 << 16); a1 += __uint_as_float(r7 & 0xffff0000u); }
  }
  float sc = 1.0f / (float)((deg > 0) ? deg : 1);
  unsigned h0 = f2bf(a0 * sc), h1 = f2bf(a1 * sc);
  *(unsigned*)(G.agg + (size_t)w * 128 + ce) = h0 | (h1 << 16);
}

// ---------------- LDS-free streaming GEMM ----------------
struct Type2 {
  const unsigned short* src[4];
  const unsigned short* wtp[4];
  int nsrc, bstart, n;
  const float* bias;
  float* out;
};
struct All2 { Type2 t[4]; };

__global__ __launch_bounds__(256, 4) void rgcn_gemm_agg(All2 A) {
  const int tid = threadIdx.x;
  const int wv = tid >> 6, lane = tid & 63;
  int bid = blockIdx.x;
  int ty = (bid >= A.t[3].bstart) ? 3 : (bid >= A.t[2].bstart) ? 2
         : (bid >= A.t[1].bstart) ? 1 : 0;
  const Type2& T = A.t[ty];
  const int rb = (bid - T.bstart) * 64;
  const int n = T.n;

  int ar = rb + wv * 16 + (lane & 15);
  if (ar >= n) ar = n - 1;
  const int ach = lane >> 4;   // 0..3

  float4v acc[8];
  #pragma unroll
  for (int i = 0; i < 8; ++i) acc[i] = (float4v)0.0f;

  for (int kb = 0; kb < T.nsrc; ++kb) {
    const unsigned short* abase = T.src[kb] + (size_t)ar * 128 + ach * 8;
    short8v af[4];
    #pragma unroll
    for (int ks = 0; ks < 4; ++ks)
      af[ks] = *(const short8v*)(abase + ks * 32);
    const unsigned short* wbase = T.wtp[kb] + (size_t)(lane & 15) * 128 + ach * 8;
    #pragma unroll
    for (int ct = 0; ct < 8; ++ct) {
      short8v bfr[4];
      #pragma unroll
      for (int ks = 0; ks < 4; ++ks)
        bfr[ks] = *(const short8v*)(wbase + (size_t)ct * 2048 + ks * 32);
      #pragma unroll
      for (int ks = 0; ks < 4; ++ks)
        acc[ct] = __builtin_amdgcn_mfma_f32_16x16x32_bf16(af[ks], bfr[ks], acc[ct], 0, 0, 0);
    }
  }
  #pragma unroll
  for (int ct = 0; ct < 8; ++ct) {
    #pragma unroll
    for (int i = 0; i < 4; ++i) {
      int row = wv * 16 + (lane >> 4) * 4 + i;
      int g = rb + row;
      if (g < n) {
        int col = ct * 16 + (lane & 15);
        T.out[(size_t)g * 128 + col] = acc[ct][i] + T.bias[col];
      }
    }
  }
}

// ---------------- fallback fused kernel (R4) ----------------
struct GemmSrc { const float* x; const unsigned short* xb;
                 const unsigned short* wt; int cntBase; };
struct TypeArgs {
  GemmSrc s[4];
  int nsrc, bstart, n;
  const float* bias;
  float* out;
};
struct AllArgs {
  TypeArgs t[4];
  const int* offs;
  const int* cnt;
  const int* csr;
};

#define LD4(p) (*(const float4v*)(p))

template <int BF>
__global__ __launch_bounds__(256, 4) void rgcn_gemm(AllArgs A) {
  __shared__ unsigned short a_lds[64 * 128];
  const int tid = threadIdx.x;
  const int wv = tid >> 6, lane = tid & 63;

  int bid = blockIdx.x;
  int ty = (bid >= A.t[3].bstart) ? 3 : (bid >= A.t[2].bstart) ? 2
         : (bid >= A.t[1].bstart) ? 1 : 0;
  const TypeArgs& T = A.t[ty];
  const int rb = (bid - T.bstart) * 64;
  const int n = T.n;

  float4v acc[8];
  #pragma unroll
  for (int i = 0; i < 8; ++i) acc[i] = (float4v)0.0f;

  for (int kb = 0; kb < T.nsrc; ++kb) {
    const GemmSrc S = T.s[kb];
    if (S.cntBase < 0) {
      if (BF) {
        int r = tid >> 2, cb = (tid & 3) * 64;
        int g = rb + r;
        const short8v* p = (const short8v*)(S.xb + (size_t)g * 128 + (cb >> 1));
        #pragma unroll
        for (int k = 0; k < 4; ++k) {
          short8v h = (g < n) ? p[k] : (short8v)0;
          int byte = (r * 256 + cb + k * 16) ^ ((r & 7) << 4);
          *(short8v*)((char*)a_lds + byte) = h;
        }
      } else {
        #pragma unroll
        for (int i = 0; i < 4; ++i) {
          int c = tid + i * 256;
          int r = c >> 4, cc = (c & 15) * 8;
          int g = rb + r;
          short8v hv;
          if (g < n) {
            float4v v0 = LD4(S.x + (size_t)g * 128 + cc);
            float4v v1 = LD4(S.x + (size_t)g * 128 + cc + 4);
            hv[0] = (short)f2bf(v0[0]); hv[1] = (short)f2bf(v0[1]);
            hv[2] = (short)f2bf(v0[2]); hv[3] = (short)f2bf(v0[3]);
            hv[4] = (short)f2bf(v1[0]); hv[5] = (short)f2bf(v1[1]);
            hv[6] = (short)f2bf(v1[2]); hv[7] = (short)f2bf(v1[3]);
          } else hv = (short8v)0;
          int byte = r * 256 + cc * 2; byte ^= (r & 7) << 4;
          *(short8v*)((char*)a_lds + byte) = hv;
        }
      }
    } else if (BF) {
      const int r = tid >> 2;
      const int c0 = (tid & 3) * 32;
      int g = rb + r;
      int gd = S.cntBase + ((g < n) ? g : 0);
      int st = A.offs[gd];
      int deg = (g < n) ? A.cnt[gd] : 0;
      float4v a0 = (float4v)0.f, a1 = (float4v)0.f, a2 = (float4v)0.f,
              a3 = (float4v)0.f, a4 = (float4v)0.f, a5 = (float4v)0.f,
              a6 = (float4v)0.f, a7 = (float4v)0.f;
      int j = 0;
      for (; j + 2 <= deg; j += 2) {
        int i0 = A.csr[st + j], i1 = A.csr[st + j + 1];
        const short8v* p0 = (const short8v*)(S.xb + (size_t)i0 * 128 + c0);
        const short8v* p1 = (const short8v*)(S.xb + (size_t)i1 * 128 + c0);
        short8v h0 = p0[0], h1 = p0[1], h2 = p0[2], h3 = p0[3];
        short8v k0 = p1[0], k1 = p1[1], k2 = p1[2], k3 = p1[3];
        acc8(a0, a1, h0); acc8(a2, a3, h1); acc8(a4, a5, h2); acc8(a6, a7, h3);
        acc8(a0, a1, k0); acc8(a2, a3, k1); acc8(a4, a5, k2); acc8(a6, a7, k3);
      }
      if (j < deg) {
        int i0 = A.csr[st + j];
        const short8v* p0 = (const short8v*)(S.xb + (size_t)i0 * 128 + c0);
        short8v h0 = p0[0], h1 = p0[1], h2 = p0[2], h3 = p0[3];
        acc8(a0, a1, h0); acc8(a2, a3, h1); acc8(a4, a5, h2); acc8(a6, a7, h3);
      }
      float sc = 1.0f / (float)((deg > 0) ? deg : 1);
      a0 *= sc; a1 *= sc; a2 *= sc; a3 *= sc;
      a4 *= sc; a5 *= sc; a6 *= sc; a7 *= sc;
      short8v o0, o1, o2, o3;
      o0[0] = (short)f2bf(a0[0]); o0[1] = (short)f2bf(a0[1]);
      o0[2] = (short)f2bf(a0[2]); o0[3] = (short)f2bf(a0[3]);
      o0[4] = (short)f2bf(a1[0]); o0[5] = (short)f2bf(a1[1]);
      o0[6] = (short)f2bf(a1[2]); o0[7] = (short)f2bf(a1[3]);
      o1[0] = (short)f2bf(a2[0]); o1[1] = (short)f2bf(a2[1]);
      o1[2] = (short)f2bf(a2[2]); o1[3] = (short)f2bf(a2[3]);
      o1[4] = (short)f2bf(a3[0]); o1[5] = (short)f2bf(a3[1]);
      o1[6] = (short)f2bf(a3[2]); o1[7] = (short)f2bf(a3[3]);
      o2[0] = (short)f2bf(a4[0]); o2[1] = (short)f2bf(a4[1]);
      o2[2] = (short)f2bf(a4[2]); o2[3] = (short)f2bf(a4[3]);
      o2[4] = (short)f2bf(a5[0]); o2[5] = (short)f2bf(a5[1]);
      o2[6] = (short)f2bf(a5[2]); o2[7] = (short)f2bf(a5[3]);
      o3[0] = (short)f2bf(a6[0]); o3[1] = (short)f2bf(a6[1]);
      o3[2] = (short)f2bf(a6[2]); o3[3] = (short)f2bf(a6[3]);
      o3[4] = (short)f2bf(a7[0]); o3[5] = (short)f2bf(a7[1]);
      o3[6] = (short)f2bf(a7[2]); o3[7] = (short)f2bf(a7[3]);
      int bbase = r * 256 + c0 * 2;
      int sw = (r & 7) << 4;
      *(short8v*)((char*)a_lds + ((bbase) ^ sw)) = o0;
      *(short8v*)((char*)a_lds + ((bbase + 16) ^ sw)) = o1;
      *(short8v*)((char*)a_lds + ((bbase + 32) ^ sw)) = o2;
      *(short8v*)((char*)a_lds + ((bbase + 48) ^ sw)) = o3;
    } else {
      const int q = lane >> 4;
      const int c0 = (lane & 15) * 8;
      int stA[4], dgA[4];
      #pragma unroll
      for (int rd = 0; rd < 4; ++rd) {
        int r = wv * 16 + rd * 4 + q;
        int g = rb + r;
        int gc = (g < n) ? g : 0;
        int gd = S.cntBase + gc;
        stA[rd] = A.offs[gd];
        dgA[rd] = (g < n) ? A.cnt[gd] : 0;
      }
      #pragma unroll
      for (int rd = 0; rd < 4; ++rd) {
        int r = wv * 16 + rd * 4 + q;
        int st = stA[rd], deg = dgA[rd];
        float a0 = 0.f, a1 = 0.f, a2 = 0.f, a3 = 0.f;
        float a4 = 0.f, a5 = 0.f, a6 = 0.f, a7 = 0.f;
        int j = 0;
        for (; j + 2 <= deg; j += 2) {
          int s0 = A.csr[st + j], s1 = A.csr[st + j + 1];
          const float* p0 = S.x + (size_t)s0 * 128 + c0;
          const float* p1 = S.x + (size_t)s1 * 128 + c0;
          float4v u0 = LD4(p0), u1 = LD4(p0 + 4);
          float4v v0 = LD4(p1), v1 = LD4(p1 + 4);
          a0 += u0[0] + v0[0]; a1 += u0[1] + v0[1];
          a2 += u0[2] + v0[2]; a3 += u0[3] + v0[3];
          a4 += u1[0] + v1[0]; a5 += u1[1] + v1[1];
          a6 += u1[2] + v1[2]; a7 += u1[3] + v1[3];
        }
        if (j < deg) {
          int s0 = A.csr[st + j];
          const float* p0 = S.x + (size_t)s0 * 128 + c0;
          float4v u0 = LD4(p0), u1 = LD4(p0 + 4);
          a0 += u0[0]; a1 += u0[1]; a2 += u0[2]; a3 += u0[3];
          a4 += u1[0]; a5 += u1[1]; a6 += u1[2]; a7 += u1[3];
        }
        float sc = 1.0f / (float)((deg > 0) ? deg : 1);
        short8v hv;
        hv[0] = (short)f2bf(a0 * sc); hv[1] = (short)f2bf(a1 * sc);
        hv[2] = (short)f2bf(a2 * sc); hv[3] = (short)f2bf(a3 * sc);
        hv[4] = (short)f2bf(a4 * sc); hv[5] = (short)f2bf(a5 * sc);
        hv[6] = (short)f2bf(a6 * sc); hv[7] = (short)f2bf(a7 * sc);
        int byte = r * 256 + c0 * 2; byte ^= (r & 7) << 4;
        *(short8v*)((char*)a_lds + byte) = hv;
      }
    }
    __syncthreads();
    short8v af[4];
    #pragma unroll
    for (int ks = 0; ks < 4; ++ks) {
      int r = wv * 16 + (lane & 15);
      int ch = ks * 4 + (lane >> 4);
      int byte = r * 256 + ch * 16; byte ^= (r & 7) << 4;
      af[ks] = *(const short8v*)((const char*)a_lds + byte);
    }
    const unsigned short* wbase = S.wt + (size_t)(lane & 15) * 128
                                + (size_t)(lane >> 4) * 8;
    #pragma unroll
    for (int ct = 0; ct < 8; ++ct) {
      short8v bfr[4];
      #pragma unroll
      for (int ks = 0; ks < 4; ++ks)
        bfr[ks] = *(const short8v*)(wbase + (size_t)ct * 16 * 128 + ks * 32);
      #pragma unroll
      for (int ks = 0; ks < 4; ++ks)
        acc[ct] = __builtin_amdgcn_mfma_f32_16x16x32_bf16(af[ks], bfr[ks], acc[ct], 0, 0, 0);
    }
    __syncthreads();
  }
  #pragma unroll
  for (int ct = 0; ct < 8; ++ct) {
    #pragma unroll
    for (int i = 0; i < 4; ++i) {
      int row = wv * 16 + (lane >> 4) * 4 + i;
      int g = rb + row;
      if (g < n) {
        int col = ct * 16 + (lane & 15);
        T.out[(size_t)g * 128 + col] = acc[ct][i] + T.bias[col];
      }
    }
  }
}

extern "C" void kernel_launch(void* const* d_in, const int* in_sizes, int n_in,
                              void* d_out, int out_size, void* d_ws, size_t ws_size,
                              hipStream_t stream) {
  const float* x_author = (const float*)d_in[0];
  const float* x_fos    = (const float*)d_in[1];
  const float* x_inst   = (const float*)d_in[2];
  const float* x_paper  = (const float*)d_in[3];

  Rels R;
  const int E[7]  = {150000, 150000, 500000, 500000, 1000000, 500000, 500000};
  const int ND[7] = {N_INST, N_AUTHOR, N_PAPER, N_AUTHOR, N_PAPER, N_FOS, N_PAPER};
  int base = 0;
  for (int r = 0; r < 7; ++r) {
    R.r[r].src = (const int*)d_in[4 + 2 * r];
    R.r[r].dst = (const int*)d_in[5 + 2 * r];
    R.r[r].E = E[r];
    R.r[r].base = base;
    base += ND[r];
  }

  char* ws = (char*)d_ws;
  int* cnt    = (int*)(ws + O_CNT);
  int* offs   = (int*)(ws + O_OFFS);
  int* cursor = (int*)(ws + O_CURSOR);
  int* btot   = (int*)(ws + O_BTOT);
  int* csr    = (int*)(ws + O_CSR);
  unsigned short* wt = (unsigned short*)(ws + O_WT);
  unsigned short* xbA = (unsigned short*)(ws + XB_AUTHOR);
  unsigned short* xbF = (unsigned short*)(ws + XB_FOS);
  unsigned short* xbI = (unsigned short*)(ws + XB_INST);
  unsigned short* xbP = (unsigned short*)(ws + XB_PAPER);
  unsigned short* agg = (unsigned short*)(ws + O_AGG);

  const int useBF  = (ws_size >= WS_NEED_BF) ? 1 : 0;
  const int useAGG = (ws_size >= WS_NEED_AGG) ? 1 : 0;

  WPtrs WP;
  WP.w[0] = (const float*)d_in[18];
  WP.w[1] = (const float*)d_in[20];
  WP.w[2] = (const float*)d_in[22];
  WP.w[3] = (const float*)d_in[24];
  for (int r = 0; r < 7; ++r) WP.w[4 + r] = (const float*)d_in[26 + r];

  XCvt xcA = {x_author, xbA, N_AUTHOR * 16};
  XCvt xcF = {x_fos,    xbF, N_FOS * 16};
  XCvt xcI = {x_inst,   xbI, N_INST * 16};
  XCvt xcP = {x_paper,  xbP, N_PAPER * 16};

  prep<<<2048, 256, 0, stream>>>(WP, wt, cnt, xcA, xcF, xcI, xcP, useBF);
  count_k<<<2048, 256, 0, stream>>>(R, cnt);
  scan1<<<410, 256, 0, stream>>>(cnt, offs, btot, NCNT);
  scan23<<<1024, 512, 0, stream>>>(offs, cursor, btot, 410, NCNT);
  fill_k<<<2048, 256, 0, stream>>>(R, cursor, csr);

  float* out = (float*)d_out;
  const int B_AFF = 0, B_ITA = 8000, B_WRITES = 108000, B_PTA = 308000,
            B_CITES = 408000, B_TOPIC = 608000, B_FTP = 638000;

  const int NB_AUTHOR = (N_AUTHOR + 63) / 64;
  const int NB_FOS    = (N_FOS + 63) / 64;
  const int NB_INST   = (N_INST + 63) / 64;
  const int NB_PAPER  = (N_PAPER + 63) / 64;
  const int NB_TOTAL = NB_AUTHOR + NB_FOS + NB_INST + NB_PAPER;

  if (useAGG) {
    AggArgs GA;
    GA.xb[0] = xbA; GA.xb[1] = xbI; GA.xb[2] = xbA; GA.xb[3] = xbP;
    GA.xb[4] = xbP; GA.xb[5] = xbP; GA.xb[6] = xbF;
    GA.offs = offs; GA.cnt = cnt; GA.csr = csr; GA.agg = agg;
    agg_k<<<NCNT / 4, 256, 0, stream>>>(GA);

    All2 A2;
    for (int t = 0; t < 4; ++t)
      for (int i = 0; i < 4; ++i) { A2.t[t].src[i] = nullptr; A2.t[t].wtp[i] = nullptr; }

    A2.t[0].src[0] = xbA;                        A2.t[0].wtp[0] = wt + 0 * 16384;
    A2.t[0].src[1] = agg + (size_t)B_ITA * 128;  A2.t[0].wtp[1] = wt + 5 * 16384;
    A2.t[0].src[2] = agg + (size_t)B_PTA * 128;  A2.t[0].wtp[2] = wt + 7 * 16384;
    A2.t[0].nsrc = 3; A2.t[0].bstart = 0; A2.t[0].n = N_AUTHOR;
    A2.t[0].bias = (const float*)d_in[19]; A2.t[0].out = out;

    A2.t[1].src[0] = xbF;                          A2.t[1].wtp[0] = wt + 1 * 16384;
    A2.t[1].src[1] = agg + (size_t)B_TOPIC * 128;  A2.t[1].wtp[1] = wt + 9 * 16384;
    A2.t[1].nsrc = 2; A2.t[1].bstart = NB_AUTHOR; A2.t[1].n = N_FOS;
    A2.t[1].bias = (const float*)d_in[21]; A2.t[1].out = out + (size_t)100000 * 128;

    A2.t[2].src[0] = xbI;                        A2.t[2].wtp[0] = wt + 2 * 16384;
    A2.t[2].src[1] = agg + (size_t)B_AFF * 128;  A2.t[2].wtp[1] = wt + 4 * 16384;
    A2.t[2].nsrc = 2; A2.t[2].bstart = NB_AUTHOR + NB_FOS; A2.t[2].n = N_INST;
    A2.t[2].bias = (const float*)d_in[23]; A2.t[2].out = out + (size_t)130000 * 128;

    A2.t[3].src[0] = xbP;                           A2.t[3].wtp[0] = wt + 3 * 16384;
    A2.t[3].src[1] = agg + (size_t)B_WRITES * 128;  A2.t[3].wtp[1] = wt + 6 * 16384;
    A2.t[3].src[2] = agg + (size_t)B_CITES * 128;   A2.t[3].wtp[2] = wt + 8 * 16384;
    A2.t[3].src[3] = agg + (size_t)B_FTP * 128;     A2.t[3].wtp[3] = wt + 10 * 16384;
    A2.t[3].nsrc = 4; A2.t[3].bstart = NB_AUTHOR + NB_FOS + NB_INST; A2.t[3].n = N_PAPER;
    A2.t[3].bias = (const float*)d_in[25]; A2.t[3].out = out + (size_t)138000 * 128;

    rgcn_gemm_agg<<<NB_TOTAL, 256, 0, stream>>>(A2);
  } else {
    AllArgs A;
    A.offs = offs; A.cnt = cnt; A.csr = csr;
    for (int t = 0; t < 4; ++t)
      for (int i = 0; i < 4; ++i) A.t[t].s[i] = GemmSrc{nullptr, nullptr, nullptr, 0};

    A.t[0].s[0] = GemmSrc{x_author, xbA, wt + 0 * 16384, -1};
    A.t[0].s[1] = GemmSrc{x_inst,   xbI, wt + 5 * 16384, B_ITA};
    A.t[0].s[2] = GemmSrc{x_paper,  xbP, wt + 7 * 16384, B_PTA};
    A.t[0].nsrc = 3; A.t[0].bstart = 0; A.t[0].n = N_AUTHOR;
    A.t[0].bias = (const float*)d_in[19]; A.t[0].out = out;

    A.t[1].s[0] = GemmSrc{x_fos,   xbF, wt + 1 * 16384, -1};
    A.t[1].s[1] = GemmSrc{x_paper, xbP, wt + 9 * 16384, B_TOPIC};
    A.t[1].nsrc = 2; A.t[1].bstart = NB_AUTHOR; A.t[1].n = N_FOS;
    A.t[1].bias = (const float*)d_in[21]; A.t[1].out = out + (size_t)100000 * 128;

    A.t[2].s[0] = GemmSrc{x_inst,   xbI, wt + 2 * 16384, -1};
    A.t[2].s[1] = GemmSrc{x_author, xbA, wt + 4 * 16384, B_AFF};
    A.t[2].nsrc = 2; A.t[2].bstart = NB_AUTHOR + NB_FOS; A.t[2].n = N_INST;
    A.t[2].bias = (const float*)d_in[23]; A.t[2].out = out + (size_t)130000 * 128;

    A.t[3].s[0] = GemmSrc{x_paper,  xbP, wt + 3 * 16384, -1};
    A.t[3].s[1] = GemmSrc{x_author, xbA, wt + 6 * 16384, B_WRITES};
    A.t[3].s[2] = GemmSrc{x_paper,  xbP, wt + 8 * 16384, B_CITES};
    A.t[3].s[3] = GemmSrc{x_fos,    xbF, wt + 10 * 16384, B_FTP};
    A.t[3].nsrc = 4; A.t[3].bstart = NB_AUTHOR + NB_FOS + NB_INST; A.t[3].n = N_PAPER;
    A.t[3].bias = (const float*)d_in[25]; A.t[3].out = out + (size_t)138000 * 128;

    if (useBF)
      rgcn_gemm<1><<<NB_TOTAL, 256, 0, stream>>>(A);
    else
      rgcn_gemm<0><<<NB_TOTAL, 256, 0, stream>>>(A);
  }
}

// Round 6
// 1048.343 us; speedup vs baseline: 1.0249x; 1.0249x over previous
//
#include <hip/hip_runtime.h>

#define N_AUTHOR 100000
#define N_FOS    30000
#define N_INST   8000
#define N_PAPER  200000

typedef __attribute__((ext_vector_type(8))) short short8v;
typedef __attribute__((ext_vector_type(4))) float float4v;

__device__ __forceinline__ unsigned short f2bf(float f) {
  unsigned u = __float_as_uint(f);
  u = u + 0x7fffu + ((u >> 16) & 1u);
  return (unsigned short)(u >> 16);
}
#define BF2F(s) __uint_as_float(((unsigned)(unsigned short)(s)) << 16)

__device__ __forceinline__ void acc8(float4v& x, float4v& y, short8v h) {
  x[0] += BF2F(h[0]); x[1] += BF2F(h[1]); x[2] += BF2F(h[2]); x[3] += BF2F(h[3]);
  y[0] += BF2F(h[4]); y[1] += BF2F(h[5]); y[2] += BF2F(h[6]); y[3] += BF2F(h[7]);
}

// ---------------- workspace layout (bytes) ----------------
#define O_CNT    0
#define O_OFFS   3352000
#define O_CURSOR 6704000
#define O_BTOT   10056000
#define O_CSR    10060096
#define O_WT     23260096
#define XB_AUTHOR 23620544
#define XB_FOS    49220544
#define XB_INST   56900544
#define XB_PAPER  58948544
#define O_AGG     110148544
#define WS_NEED_BF  110148544ULL
#define WS_NEED_AGG 324676544ULL
#define NCNT     838000

struct RelTab { const int* src; const int* dst; int E; int base; };
struct Rels { RelTab r[7]; };
struct WPtrs { const float* w[11]; };
struct XCvt { const float* x; unsigned short* xb; int n8; };

// merged prep: W transpose+bf16, x fp32->bf16, edge COUNT (cnt pre-zeroed by memset)
__global__ void prep(WPtrs P, unsigned short* __restrict__ wt,
                     int* __restrict__ cnt, XCvt x0, XCvt x1, XCvt x2, XCvt x3,
                     Rels R, int doX) {
  int gsz = gridDim.x * blockDim.x;
  int gtid = blockIdx.x * blockDim.x + threadIdx.x;
  for (int i = gtid; i < 11 * 16384; i += gsz) {
    int mat = i >> 14, rem = i & 16383;
    int k = rem >> 7, n = rem & 127;
    wt[mat * 16384 + n * 128 + k] = f2bf(P.w[mat][rem]);
  }
  if (doX) {
    XCvt xc[4] = {x0, x1, x2, x3};
    #pragma unroll
    for (int a = 0; a < 4; ++a) {
      const float* xp = xc[a].x;
      short8v* xbp = (short8v*)xc[a].xb;
      int n8 = xc[a].n8;
      for (int i = gtid; i < n8; i += gsz) {
        float4v v0 = *(const float4v*)(xp + (size_t)i * 8);
        float4v v1 = *(const float4v*)(xp + (size_t)i * 8 + 4);
        short8v h;
        h[0] = (short)f2bf(v0[0]); h[1] = (short)f2bf(v0[1]);
        h[2] = (short)f2bf(v0[2]); h[3] = (short)f2bf(v0[3]);
        h[4] = (short)f2bf(v1[0]); h[5] = (short)f2bf(v1[1]);
        h[6] = (short)f2bf(v1[2]); h[7] = (short)f2bf(v1[3]);
        xbp[i] = h;
      }
    }
  }
  // edge counting (fused)
  for (int rr = 0; rr < 7; ++rr) {
    const int* dst = R.r[rr].dst;
    int E = R.r[rr].E, base = R.r[rr].base;
    for (int e = gtid; e < E; e += gsz) atomicAdd(&cnt[base + dst[e]], 1);
  }
}

__global__ void scan1(const int* __restrict__ cnt, int* __restrict__ offs,
                      int* __restrict__ btot, int n) {
  __shared__ int sh[256];
  int tid = threadIdx.x;
  int base = blockIdx.x * 2048 + tid * 8;
  int v[8]; int s = 0;
  #pragma unroll
  for (int i = 0; i < 8; ++i) { v[i] = (base + i < n) ? cnt[base + i] : 0; s += v[i]; }
  sh[tid] = s; __syncthreads();
  for (int off = 1; off < 256; off <<= 1) {
    int t = (tid >= off) ? sh[tid - off] : 0;
    __syncthreads();
    sh[tid] += t;
    __syncthreads();
  }
  int excl = sh[tid] - s;
  if (tid == 255) btot[blockIdx.x] = sh[255];
  int run = excl;
  #pragma unroll
  for (int i = 0; i < 8; ++i) { if (base + i < n) offs[base + i] = run; run += v[i]; }
}

__global__ void scan23(int* __restrict__ offs, int* __restrict__ cursor,
                       const int* __restrict__ btot, int nb, int n) {
  __shared__ int sh[512];
  int tid = threadIdx.x;
  int v = (tid < nb) ? btot[tid] : 0;
  sh[tid] = v; __syncthreads();
  for (int off = 1; off < 512; off <<= 1) {
    int t = (tid >= off) ? sh[tid - off] : 0;
    __syncthreads();
    sh[tid] += t;
    __syncthreads();
  }
  int excl = sh[tid] - v;
  __syncthreads();
  sh[tid] = excl;
  __syncthreads();
  int gsz = gridDim.x * 512;
  for (int idx = blockIdx.x * 512 + tid; idx < n; idx += gsz) {
    int val = offs[idx] + sh[idx >> 11];
    offs[idx] = val;
    cursor[idx] = val;
  }
}

__global__ void fill_k(Rels R, int* __restrict__ cursor, int* __restrict__ csr) {
  int gsz = gridDim.x * blockDim.x;
  int gtid = blockIdx.x * blockDim.x + threadIdx.x;
  for (int rr = 0; rr < 7; ++rr) {
    const int* src = R.r[rr].src;
    const int* dst = R.r[rr].dst;
    int E = R.r[rr].E, base = R.r[rr].base;
    for (int e = gtid; e < E; e += gsz) {
      int p = atomicAdd(&cursor[base + dst[e]], 1);
      csr[p] = src[e];
    }
  }
}

// ---------------- wave-per-row aggregation ----------------
struct AggArgs {
  const unsigned short* xb[7];
  const int* offs; const int* cnt; const int* csr;
  unsigned short* agg;
};

__global__ __launch_bounds__(256, 8) void agg_k(AggArgs G) {
  const int w = blockIdx.x * 4 + (threadIdx.x >> 6);
  const int lane = threadIdx.x & 63;
  int rel = (w >= 638000) ? 6 : (w >= 608000) ? 5 : (w >= 408000) ? 4
          : (w >= 308000) ? 3 : (w >= 108000) ? 2 : (w >= 8000) ? 1 : 0;
  const unsigned short* xb = G.xb[rel];
  const int st = G.offs[w];
  const int deg = G.cnt[w];
  const int ce = lane * 2;
  float a0 = 0.f, a1 = 0.f;
  for (int j = 0; j < deg; j += 8) {
    int rem = deg - j;
    int nb = (rem > 8) ? 8 : rem;
    int vidx = 0;
    if (lane < nb) vidx = G.csr[st + j + lane];
    unsigned r0 = 0, r1 = 0, r2 = 0, r3 = 0, r4 = 0, r5 = 0, r6 = 0, r7 = 0;
    int s;
    if (nb > 0) { s = __builtin_amdgcn_readlane(vidx, 0); r0 = *(const unsigned*)(xb + (size_t)s * 128 + ce); }
    if (nb > 1) { s = __builtin_amdgcn_readlane(vidx, 1); r1 = *(const unsigned*)(xb + (size_t)s * 128 + ce); }
    if (nb > 2) { s = __builtin_amdgcn_readlane(vidx, 2); r2 = *(const unsigned*)(xb + (size_t)s * 128 + ce); }
    if (nb > 3) { s = __builtin_amdgcn_readlane(vidx, 3); r3 = *(const unsigned*)(xb + (size_t)s * 128 + ce); }
    if (nb > 4) { s = __builtin_amdgcn_readlane(vidx, 4); r4 = *(const unsigned*)(xb + (size_t)s * 128 + ce); }
    if (nb > 5) { s = __builtin_amdgcn_readlane(vidx, 5); r5 = *(const unsigned*)(xb + (size_t)s * 128 + ce); }
    if (nb > 6) { s = __builtin_amdgcn_readlane(vidx, 6); r6 = *(const unsigned*)(xb + (size_t)s * 128 + ce); }
    if (nb > 7) { s = __builtin_amdgcn_readlane(vidx, 7); r7 = *(const unsigned*)(xb + (size_t)s * 128 + ce); }
    if (nb > 0) { a0 += __uint_as_float(r0 << 16); a1 += __uint_as_float(r0 & 0xffff0000u); }
    if (nb > 1) { a0 += __uint_as_float(r1 << 16); a1 += __uint_as_float(r1 & 0xffff0000u); }
    if (nb > 2) { a0 += __uint_as_float(r2 << 16); a1 += __uint_as_float(r2 & 0xffff0000u); }
    if (nb > 3) { a0 += __uint_as_float(r3 << 16); a1 += __uint_as_float(r3 & 0xffff0000u); }
    if (nb > 4) { a0 += __uint_as_float(r4 << 16); a1 += __uint_as_float(r4 & 0xffff0000u); }
    if (nb > 5) { a0 += __uint_as_float(r5 << 16); a1 += __uint_as_float(r5 & 0xffff0000u); }
    if (nb > 6) { a0 += __uint_as_float(r6 << 16); a1 += __uint_as_float(r6 & 0xffff0000u); }
    if (nb > 7) { a0 += __uint_as_float(r7 << 16); a1 += __uint_as_float(r7 & 0xffff0000u); }
  }
  float sc = 1.0f / (float)((deg > 0) ? deg : 1);
  unsigned h0 = f2bf(a0 * sc), h1 = f2bf(a1 * sc);
  *(unsigned*)(G.agg + (size_t)w * 128 + ce) = h0 | (h1 << 16);
}

// ---------------- LDS-staged streaming GEMM ----------------
struct Type2 {
  const unsigned short* src[4];
  const unsigned short* wtp[4];
  int nsrc, bstart, n;
  const float* bias;
  float* out;
};
struct All2 { Type2 t[4]; };

__device__ __forceinline__ void loadg_tile(const unsigned short* src, int rb,
                                           int n, int tid, short8v (&g)[4]) {
  #pragma unroll
  for (int p = 0; p < 4; ++p) {
    int L = tid * 16 + p * 4096;       // logical byte in 64x256B tile
    int row = L >> 8;
    int grow = rb + row; if (grow >= n) grow = n - 1;
    g[p] = *(const short8v*)((const char*)src + (size_t)grow * 256 + (L & 255));
  }
}

__global__ __launch_bounds__(256, 4) void rgcn_gemm_agg(All2 A) {
  __shared__ unsigned short a_lds[2][64 * 128];
  const int tid = threadIdx.x;
  const int wv = tid >> 6, lane = tid & 63;
  int bid = blockIdx.x;
  int ty = (bid >= A.t[3].bstart) ? 3 : (bid >= A.t[2].bstart) ? 2
         : (bid >= A.t[1].bstart) ? 1 : 0;
  const Type2& T = A.t[ty];
  const int rb = (bid - T.bstart) * 64;
  const int n = T.n;
  const int nsrc = T.nsrc;

  float4v acc[8];
  #pragma unroll
  for (int i = 0; i < 8; ++i) acc[i] = (float4v)0.0f;

  short8v g[4];
  loadg_tile(T.src[0], rb, n, tid, g);   // prologue: tile 0 -> regs
  int cur = 0;
  for (int kb = 0; kb < nsrc; ++kb) {
    // ds_write staged regs (swizzled)
    #pragma unroll
    for (int p = 0; p < 4; ++p) {
      int L = tid * 16 + p * 4096;
      int row = L >> 8;
      int phys = L ^ ((row & 7) << 4);
      *(short8v*)((char*)a_lds[cur] + phys) = g[p];
    }
    // issue next tile's global loads early (overlap with compute below)
    if (kb + 1 < nsrc) loadg_tile(T.src[kb + 1], rb, n, tid, g);
    asm volatile("s_waitcnt lgkmcnt(0)" ::: "memory");
    __builtin_amdgcn_s_barrier();
    // A fragments from LDS (swizzled)
    short8v af[4];
    #pragma unroll
    for (int ks = 0; ks < 4; ++ks) {
      int r = wv * 16 + (lane & 15);
      int ch = ks * 4 + (lane >> 4);
      int byte = (r * 256 + ch * 16) ^ ((r & 7) << 4);
      af[ks] = *(const short8v*)((const char*)a_lds[cur] + byte);
    }
    // B fragments from global WT (L2-hot) + MFMA
    const unsigned short* wbase = T.wtp[kb] + (size_t)(lane & 15) * 128
                                + (size_t)(lane >> 4) * 8;
    #pragma unroll
    for (int ct = 0; ct < 8; ++ct) {
      short8v bfr[4];
      #pragma unroll
      for (int ks = 0; ks < 4; ++ks)
        bfr[ks] = *(const short8v*)(wbase + (size_t)ct * 2048 + ks * 32);
      #pragma unroll
      for (int ks = 0; ks < 4; ++ks)
        acc[ct] = __builtin_amdgcn_mfma_f32_16x16x32_bf16(af[ks], bfr[ks], acc[ct], 0, 0, 0);
    }
    cur ^= 1;
  }
  #pragma unroll
  for (int ct = 0; ct < 8; ++ct) {
    #pragma unroll
    for (int i = 0; i < 4; ++i) {
      int row = wv * 16 + (lane >> 4) * 4 + i;
      int gg = rb + row;
      if (gg < n) {
        int col = ct * 16 + (lane & 15);
        T.out[(size_t)gg * 128 + col] = acc[ct][i] + T.bias[col];
      }
    }
  }
}

// ---------------- fallback fused kernel (R4, bf16 LDS gather) ----------------
struct GemmSrc { const float* x; const unsigned short* xb;
                 const unsigned short* wt; int cntBase; };
struct TypeArgs {
  GemmSrc s[4];
  int nsrc, bstart, n;
  const float* bias;
  float* out;
};
struct AllArgs {
  TypeArgs t[4];
  const int* offs;
  const int* cnt;
  const int* csr;
};

#define LD4(p) (*(const float4v*)(p))

__global__ __launch_bounds__(256, 4) void rgcn_gemm(AllArgs A) {
  __shared__ unsigned short a_lds[64 * 128];
  const int tid = threadIdx.x;
  const int wv = tid >> 6, lane = tid & 63;

  int bid = blockIdx.x;
  int ty = (bid >= A.t[3].bstart) ? 3 : (bid >= A.t[2].bstart) ? 2
         : (bid >= A.t[1].bstart) ? 1 : 0;
  const TypeArgs& T = A.t[ty];
  const int rb = (bid - T.bstart) * 64;
  const int n = T.n;

  float4v acc[8];
  #pragma unroll
  for (int i = 0; i < 8; ++i) acc[i] = (float4v)0.0f;

  for (int kb = 0; kb < T.nsrc; ++kb) {
    const GemmSrc S = T.s[kb];
    if (S.cntBase < 0) {
      int r = tid >> 2, cb = (tid & 3) * 64;
      int g = rb + r;
      const short8v* p = (const short8v*)(S.xb + (size_t)g * 128 + (cb >> 1));
      #pragma unroll
      for (int k = 0; k < 4; ++k) {
        short8v h = (g < n) ? p[k] : (short8v)0;
        int byte = (r * 256 + cb + k * 16) ^ ((r & 7) << 4);
        *(short8v*)((char*)a_lds + byte) = h;
      }
    } else {
      const int r = tid >> 2;
      const int c0 = (tid & 3) * 32;
      int g = rb + r;
      int gd = S.cntBase + ((g < n) ? g : 0);
      int st = A.offs[gd];
      int deg = (g < n) ? A.cnt[gd] : 0;
      float4v a0 = (float4v)0.f, a1 = (float4v)0.f, a2 = (float4v)0.f,
              a3 = (float4v)0.f, a4 = (float4v)0.f, a5 = (float4v)0.f,
              a6 = (float4v)0.f, a7 = (float4v)0.f;
      int j = 0;
      for (; j + 2 <= deg; j += 2) {
        int i0 = A.csr[st + j], i1 = A.csr[st + j + 1];
        const short8v* p0 = (const short8v*)(S.xb + (size_t)i0 * 128 + c0);
        const short8v* p1 = (const short8v*)(S.xb + (size_t)i1 * 128 + c0);
        short8v h0 = p0[0], h1 = p0[1], h2 = p0[2], h3 = p0[3];
        short8v k0 = p1[0], k1 = p1[1], k2 = p1[2], k3 = p1[3];
        acc8(a0, a1, h0); acc8(a2, a3, h1); acc8(a4, a5, h2); acc8(a6, a7, h3);
        acc8(a0, a1, k0); acc8(a2, a3, k1); acc8(a4, a5, k2); acc8(a6, a7, k3);
      }
      if (j < deg) {
        int i0 = A.csr[st + j];
        const short8v* p0 = (const short8v*)(S.xb + (size_t)i0 * 128 + c0);
        short8v h0 = p0[0], h1 = p0[1], h2 = p0[2], h3 = p0[3];
        acc8(a0, a1, h0); acc8(a2, a3, h1); acc8(a4, a5, h2); acc8(a6, a7, h3);
      }
      float sc = 1.0f / (float)((deg > 0) ? deg : 1);
      a0 *= sc; a1 *= sc; a2 *= sc; a3 *= sc;
      a4 *= sc; a5 *= sc; a6 *= sc; a7 *= sc;
      short8v o0, o1, o2, o3;
      o0[0] = (short)f2bf(a0[0]); o0[1] = (short)f2bf(a0[1]);
      o0[2] = (short)f2bf(a0[2]); o0[3] = (short)f2bf(a0[3]);
      o0[4] = (short)f2bf(a1[0]); o0[5] = (short)f2bf(a1[1]);
      o0[6] = (short)f2bf(a1[2]); o0[7] = (short)f2bf(a1[3]);
      o1[0] = (short)f2bf(a2[0]); o1[1] = (short)f2bf(a2[1]);
      o1[2] = (short)f2bf(a2[2]); o1[3] = (short)f2bf(a2[3]);
      o1[4] = (short)f2bf(a3[0]); o1[5] = (short)f2bf(a3[1]);
      o1[6] = (short)f2bf(a3[2]); o1[7] = (short)f2bf(a3[3]);
      o2[0] = (short)f2bf(a4[0]); o2[1] = (short)f2bf(a4[1]);
      o2[2] = (short)f2bf(a4[2]); o2[3] = (short)f2bf(a4[3]);
      o2[4] = (short)f2bf(a5[0]); o2[5] = (short)f2bf(a5[1]);
      o2[6] = (short)f2bf(a5[2]); o2[7] = (short)f2bf(a5[3]);
      o3[0] = (short)f2bf(a6[0]); o3[1] = (short)f2bf(a6[1]);
      o3[2] = (short)f2bf(a6[2]); o3[3] = (short)f2bf(a6[3]);
      o3[4] = (short)f2bf(a7[0]); o3[5] = (short)f2bf(a7[1]);
      o3[6] = (short)f2bf(a7[2]); o3[7] = (short)f2bf(a7[3]);
      int bbase = r * 256 + c0 * 2;
      int sw = (r & 7) << 4;
      *(short8v*)((char*)a_lds + ((bbase) ^ sw)) = o0;
      *(short8v*)((char*)a_lds + ((bbase + 16) ^ sw)) = o1;
      *(short8v*)((char*)a_lds + ((bbase + 32) ^ sw)) = o2;
      *(short8v*)((char*)a_lds + ((bbase + 48) ^ sw)) = o3;
    }
    __syncthreads();
    short8v af[4];
    #pragma unroll
    for (int ks = 0; ks < 4; ++ks) {
      int r = wv * 16 + (lane & 15);
      int ch = ks * 4 + (lane >> 4);
      int byte = r * 256 + ch * 16; byte ^= (r & 7) << 4;
      af[ks] = *(const short8v*)((const char*)a_lds + byte);
    }
    const unsigned short* wbase = S.wt + (size_t)(lane & 15) * 128
                                + (size_t)(lane >> 4) * 8;
    #pragma unroll
    for (int ct = 0; ct < 8; ++ct) {
      short8v bfr[4];
      #pragma unroll
      for (int ks = 0; ks < 4; ++ks)
        bfr[ks] = *(const short8v*)(wbase + (size_t)ct * 16 * 128 + ks * 32);
      #pragma unroll
      for (int ks = 0; ks < 4; ++ks)
        acc[ct] = __builtin_amdgcn_mfma_f32_16x16x32_bf16(af[ks], bfr[ks], acc[ct], 0, 0, 0);
    }
    __syncthreads();
  }
  #pragma unroll
  for (int ct = 0; ct < 8; ++ct) {
    #pragma unroll
    for (int i = 0; i < 4; ++i) {
      int row = wv * 16 + (lane >> 4) * 4 + i;
      int g = rb + row;
      if (g < n) {
        int col = ct * 16 + (lane & 15);
        T.out[(size_t)g * 128 + col] = acc[ct][i] + T.bias[col];
      }
    }
  }
}

extern "C" void kernel_launch(void* const* d_in, const int* in_sizes, int n_in,
                              void* d_out, int out_size, void* d_ws, size_t ws_size,
                              hipStream_t stream) {
  const float* x_author = (const float*)d_in[0];
  const float* x_fos    = (const float*)d_in[1];
  const float* x_inst   = (const float*)d_in[2];
  const float* x_paper  = (const float*)d_in[3];

  Rels R;
  const int E[7]  = {150000, 150000, 500000, 500000, 1000000, 500000, 500000};
  const int ND[7] = {N_INST, N_AUTHOR, N_PAPER, N_AUTHOR, N_PAPER, N_FOS, N_PAPER};
  int base = 0;
  for (int r = 0; r < 7; ++r) {
    R.r[r].src = (const int*)d_in[4 + 2 * r];
    R.r[r].dst = (const int*)d_in[5 + 2 * r];
    R.r[r].E = E[r];
    R.r[r].base = base;
    base += ND[r];
  }

  char* ws = (char*)d_ws;
  int* cnt    = (int*)(ws + O_CNT);
  int* offs   = (int*)(ws + O_OFFS);
  int* cursor = (int*)(ws + O_CURSOR);
  int* btot   = (int*)(ws + O_BTOT);
  int* csr    = (int*)(ws + O_CSR);
  unsigned short* wt = (unsigned short*)(ws + O_WT);
  unsigned short* xbA = (unsigned short*)(ws + XB_AUTHOR);
  unsigned short* xbF = (unsigned short*)(ws + XB_FOS);
  unsigned short* xbI = (unsigned short*)(ws + XB_INST);
  unsigned short* xbP = (unsigned short*)(ws + XB_PAPER);
  unsigned short* agg = (unsigned short*)(ws + O_AGG);

  const int useBF  = (ws_size >= WS_NEED_BF) ? 1 : 0;
  const int useAGG = (ws_size >= WS_NEED_AGG) ? 1 : 0;

  WPtrs WP;
  WP.w[0] = (const float*)d_in[18];
  WP.w[1] = (const float*)d_in[20];
  WP.w[2] = (const float*)d_in[22];
  WP.w[3] = (const float*)d_in[24];
  for (int r = 0; r < 7; ++r) WP.w[4 + r] = (const float*)d_in[26 + r];

  XCvt xcA = {x_author, xbA, N_AUTHOR * 16};
  XCvt xcF = {x_fos,    xbF, N_FOS * 16};
  XCvt xcI = {x_inst,   xbI, N_INST * 16};
  XCvt xcP = {x_paper,  xbP, N_PAPER * 16};

  hipMemsetAsync(cnt, 0, (size_t)NCNT * 4, stream);
  prep<<<2048, 256, 0, stream>>>(WP, wt, cnt, xcA, xcF, xcI, xcP, R, useBF);
  scan1<<<410, 256, 0, stream>>>(cnt, offs, btot, NCNT);
  scan23<<<1024, 512, 0, stream>>>(offs, cursor, btot, 410, NCNT);
  fill_k<<<2048, 256, 0, stream>>>(R, cursor, csr);

  float* out = (float*)d_out;
  const int B_AFF = 0, B_ITA = 8000, B_WRITES = 108000, B_PTA = 308000,
            B_CITES = 408000, B_TOPIC = 608000, B_FTP = 638000;

  const int NB_AUTHOR = (N_AUTHOR + 63) / 64;
  const int NB_FOS    = (N_FOS + 63) / 64;
  const int NB_INST   = (N_INST + 63) / 64;
  const int NB_PAPER  = (N_PAPER + 63) / 64;
  const int NB_TOTAL = NB_AUTHOR + NB_FOS + NB_INST + NB_PAPER;

  if (useAGG) {
    AggArgs GA;
    GA.xb[0] = xbA; GA.xb[1] = xbI; GA.xb[2] = xbA; GA.xb[3] = xbP;
    GA.xb[4] = xbP; GA.xb[5] = xbP; GA.xb[6] = xbF;
    GA.offs = offs; GA.cnt = cnt; GA.csr = csr; GA.agg = agg;
    agg_k<<<NCNT / 4, 256, 0, stream>>>(GA);

    All2 A2;
    for (int t = 0; t < 4; ++t)
      for (int i = 0; i < 4; ++i) { A2.t[t].src[i] = nullptr; A2.t[t].wtp[i] = nullptr; }

    A2.t[0].src[0] = xbA;                        A2.t[0].wtp[0] = wt + 0 * 16384;
    A2.t[0].src[1] = agg + (size_t)B_ITA * 128;  A2.t[0].wtp[1] = wt + 5 * 16384;
    A2.t[0].src[2] = agg + (size_t)B_PTA * 128;  A2.t[0].wtp[2] = wt + 7 * 16384;
    A2.t[0].nsrc = 3; A2.t[0].bstart = 0; A2.t[0].n = N_AUTHOR;
    A2.t[0].bias = (const float*)d_in[19]; A2.t[0].out = out;

    A2.t[1].src[0] = xbF;                          A2.t[1].wtp[0] = wt + 1 * 16384;
    A2.t[1].src[1] = agg + (size_t)B_TOPIC * 128;  A2.t[1].wtp[1] = wt + 9 * 16384;
    A2.t[1].nsrc = 2; A2.t[1].bstart = NB_AUTHOR; A2.t[1].n = N_FOS;
    A2.t[1].bias = (const float*)d_in[21]; A2.t[1].out = out + (size_t)100000 * 128;

    A2.t[2].src[0] = xbI;                        A2.t[2].wtp[0] = wt + 2 * 16384;
    A2.t[2].src[1] = agg + (size_t)B_AFF * 128;  A2.t[2].wtp[1] = wt + 4 * 16384;
    A2.t[2].nsrc = 2; A2.t[2].bstart = NB_AUTHOR + NB_FOS; A2.t[2].n = N_INST;
    A2.t[2].bias = (const float*)d_in[23]; A2.t[2].out = out + (size_t)130000 * 128;

    A2.t[3].src[0] = xbP;                           A2.t[3].wtp[0] = wt + 3 * 16384;
    A2.t[3].src[1] = agg + (size_t)B_WRITES * 128;  A2.t[3].wtp[1] = wt + 6 * 16384;
    A2.t[3].src[2] = agg + (size_t)B_CITES * 128;   A2.t[3].wtp[2] = wt + 8 * 16384;
    A2.t[3].src[3] = agg + (size_t)B_FTP * 128;     A2.t[3].wtp[3] = wt + 10 * 16384;
    A2.t[3].nsrc = 4; A2.t[3].bstart = NB_AUTHOR + NB_FOS + NB_INST; A2.t[3].n = N_PAPER;
    A2.t[3].bias = (const float*)d_in[25]; A2.t[3].out = out + (size_t)138000 * 128;

    rgcn_gemm_agg<<<NB_TOTAL, 256, 0, stream>>>(A2);
  } else {
    AllArgs A;
    A.offs = offs; A.cnt = cnt; A.csr = csr;
    for (int t = 0; t < 4; ++t)
      for (int i = 0; i < 4; ++i) A.t[t].s[i] = GemmSrc{nullptr, nullptr, nullptr, 0};

    A.t[0].s[0] = GemmSrc{x_author, xbA, wt + 0 * 16384, -1};
    A.t[0].s[1] = GemmSrc{x_inst,   xbI, wt + 5 * 16384, B_ITA};
    A.t[0].s[2] = GemmSrc{x_paper,  xbP, wt + 7 * 16384, B_PTA};
    A.t[0].nsrc = 3; A.t[0].bstart = 0; A.t[0].n = N_AUTHOR;
    A.t[0].bias = (const float*)d_in[19]; A.t[0].out = out;

    A.t[1].s[0] = GemmSrc{x_fos,   xbF, wt + 1 * 16384, -1};
    A.t[1].s[1] = GemmSrc{x_paper, xbP, wt + 9 * 16384, B_TOPIC};
    A.t[1].nsrc = 2; A.t[1].bstart = NB_AUTHOR; A.t[1].n = N_FOS;
    A.t[1].bias = (const float*)d_in[21]; A.t[1].out = out + (size_t)100000 * 128;

    A.t[2].s[0] = GemmSrc{x_inst,   xbI, wt + 2 * 16384, -1};
    A.t[2].s[1] = GemmSrc{x_author, xbA, wt + 4 * 16384, B_AFF};
    A.t[2].nsrc = 2; A.t[2].bstart = NB_AUTHOR + NB_FOS; A.t[2].n = N_INST;
    A.t[2].bias = (const float*)d_in[23]; A.t[2].out = out + (size_t)130000 * 128;

    A.t[3].s[0] = GemmSrc{x_paper,  xbP, wt + 3 * 16384, -1};
    A.t[3].s[1] = GemmSrc{x_author, xbA, wt + 6 * 16384, B_WRITES};
    A.t[3].s[2] = GemmSrc{x_paper,  xbP, wt + 8 * 16384, B_CITES};
    A.t[3].s[3] = GemmSrc{x_fos,    xbF, wt + 10 * 16384, B_FTP};
    A.t[3].nsrc = 4; A.t[3].bstart = NB_AUTHOR + NB_FOS + NB_INST; A.t[3].n = N_PAPER;
    A.t[3].bias = (const float*)d_in[25]; A.t[3].out = out + (size_t)138000 * 128;

    rgcn_gemm<<<NB_TOTAL, 256, 0, stream>>>(A);
  }
}